// Round 7
// baseline (298.091 us; speedup 1.0000x reference)
//
#include <hip/hip_runtime.h>
#include <math.h>

#define HOP 256
#define PI2F 6.28318530717958647692f
#define PADZ(i) ((i) + ((i) >> 4))

#define C16 0.92387953251128675613f   // cos(pi/8)
#define S16 0.38268343236508977173f   // sin(pi/8)
#define RH  0.70710678118654752440f   // sqrt(2)/2

// wave-internal LDS ordering fence: drain LDS queue, pin scheduler.
#define FENCE() do { asm volatile("s_waitcnt lgkmcnt(0)" ::: "memory"); \
                     __builtin_amdgcn_sched_barrier(0); } while (0)

// ---------------- one-time tables (recomputed every launch into d_ws) --------
// win[2048]: periodic Hann
// gtwA[1024]: gtwA[64*s + l] = e^{-j2pi*l*s/1024}, l in [0,64), s in [0,16)
//             (also serves stage B: w64^{n0*u} = gtwA[64*u + 16*n0])
// guw[513]:  e^{-j2pi*k/2048} untangle twiddles
// cnt: zeroed completion counter for the fused-median last-block pattern
__global__ __launch_bounds__(256) void precompute(float* __restrict__ win,
                                                  float2* __restrict__ gtwA,
                                                  float2* __restrict__ guw,
                                                  unsigned* __restrict__ cnt) {
  const int i = blockIdx.x * blockDim.x + threadIdx.x;
  if (i < 2048) win[i] = 0.5f * (1.0f - cosf(PI2F * (float)i / 2048.0f));
  if (i < 1024) {
    const int s2 = i >> 6, l = i & 63;
    float s, c; sincosf(-PI2F * (float)(l * s2) / 1024.0f, &s, &c);
    gtwA[i] = make_float2(c, s);
  }
  if (i < 513) {
    float s, c; sincosf(-PI2F * (float)i / 2048.0f, &s, &c);
    guw[i] = make_float2(c, s);
  }
  if (i == 0) *cnt = 0u;
}

// ---------------- complex helpers (forward convention w16 = e^{-j2pi/16}) ----
__device__ __forceinline__ float2 cadd(float2 a, float2 b){ return make_float2(a.x+b.x, a.y+b.y); }
__device__ __forceinline__ float2 csub(float2 a, float2 b){ return make_float2(a.x-b.x, a.y-b.y); }
__device__ __forceinline__ float2 cmul(float2 a, float2 b){
  return make_float2(fmaf(a.x, b.x, -a.y*b.y), fmaf(a.x, b.y, a.y*b.x));
}
__device__ __forceinline__ float2 mul_mj(float2 v){ return make_float2(v.y, -v.x); }  // *(-j)
__device__ __forceinline__ float2 mul_pj(float2 v){ return make_float2(-v.y, v.x); }  // *(+j)
// multiply by w16^e
__device__ __forceinline__ float2 tw1f(float2 v){ return make_float2(fmaf(C16,v.x, S16*v.y), fmaf(C16,v.y,-S16*v.x)); }
__device__ __forceinline__ float2 tw2f(float2 v){ return make_float2(RH*(v.x+v.y), RH*(v.y-v.x)); }
__device__ __forceinline__ float2 tw3f(float2 v){ return make_float2(fmaf(S16,v.x, C16*v.y), fmaf(S16,v.y,-C16*v.x)); }
__device__ __forceinline__ float2 tw4f(float2 v){ return make_float2(v.y, -v.x); }
__device__ __forceinline__ float2 tw6f(float2 v){ return make_float2(RH*(v.y-v.x), -RH*(v.x+v.y)); }
__device__ __forceinline__ float2 tw9f(float2 v){ return make_float2(fmaf(-C16,v.x,-S16*v.y), fmaf(S16,v.x,-C16*v.y)); }

__device__ __forceinline__ void dft4(float2 a, float2 b, float2 c, float2 d,
                                     float2& o0, float2& o1, float2& o2, float2& o3) {
  const float2 t0 = cadd(a, c), t1 = csub(a, c);
  const float2 t2 = cadd(b, d), t3 = csub(b, d);
  o0 = cadd(t0, t2);
  o2 = csub(t0, t2);
  o1 = cadd(t1, mul_mj(t3));
  o3 = cadd(t1, mul_pj(t3));
}

// in-place 16-pt DFT: v[k] = sum_j v_in[j] * w16^{jk}
__device__ __forceinline__ void dft16(float2 v[16]) {
  float2 A0[4], A1[4], A2[4], A3[4];
  dft4(v[0], v[4], v[ 8], v[12], A0[0], A0[1], A0[2], A0[3]);
  dft4(v[1], v[5], v[ 9], v[13], A1[0], A1[1], A1[2], A1[3]);
  dft4(v[2], v[6], v[10], v[14], A2[0], A2[1], A2[2], A2[3]);
  dft4(v[3], v[7], v[11], v[15], A3[0], A3[1], A3[2], A3[3]);
  dft4(A0[0],       A1[0],        A2[0],        A3[0],       v[0], v[4], v[ 8], v[12]);
  dft4(A0[1], tw1f(A1[1]), tw2f(A2[1]), tw3f(A3[1]), v[1], v[5], v[ 9], v[13]);
  dft4(A0[2], tw2f(A1[2]), tw4f(A2[2]), tw6f(A3[2]), v[2], v[6], v[10], v[14]);
  dft4(A0[3], tw3f(A1[3]), tw6f(A2[3]), tw9f(A3[3]), v[3], v[7], v[11], v[15]);
}

// 1024-pt FFT for ONE wave: input v[j] = x[l + 64 j]; output natural-order Z in
// zw[PADZ(k)]. Decomposition 1024 = 16 x 16 x 4, two LDS exchanges.
// Stage twiddles from the precomputed global table (coalesced, L1-hot).
__device__ __forceinline__ void wave_fft1024(float2* __restrict__ zw, float2 v[16],
                                             const int l,
                                             const float2* __restrict__ gtwA) {
  // stage A: z_s[l] = w1024^{l s} * sum_j x[l+64j] w16^{js}
  dft16(v);
  #pragma unroll
  for (int s = 1; s < 16; ++s) v[s] = cmul(v[s], gtwA[(s << 6) + l]);
  // exchange 1: E[s][l] at 65 s + l
  #pragma unroll
  for (int s = 0; s < 16; ++s) zw[65 * s + l] = v[s];
  FENCE();
  const int sp = l >> 2, n0 = l & 3;
  #pragma unroll
  for (int r = 0; r < 16; ++r) v[r] = zw[65 * sp + n0 + 4 * r];
  // stage B: g_u = w64^{n0 u} * sum_r z_sp[n0+4r] w16^{ru}
  dft16(v);
  #pragma unroll
  for (int u = 1; u < 16; ++u) v[u] = cmul(v[u], gtwA[(u << 6) + (n0 << 4)]);
  // exchange 2: E2[sp][u][n0] at 65 sp + 4u + n0
  #pragma unroll
  for (int u = 0; u < 16; ++u) zw[65 * sp + 4 * u + n0] = v[u];
  FENCE();
  #pragma unroll
  for (int b = 0; b < 4; ++b)
    #pragma unroll
    for (int m0 = 0; m0 < 4; ++m0)
      v[4 * b + m0] = zw[65 * sp + 16 * n0 + 4 * b + m0];
  FENCE();   // all reads retired before stores overwrite the buffer
  // final radix-4: Z[256 q2 + 64 n0 + 16 b + sp]
  #pragma unroll
  for (int b = 0; b < 4; ++b) {
    float2 o0, o1, o2, o3;
    dft4(v[4*b+0], v[4*b+1], v[4*b+2], v[4*b+3], o0, o1, o2, o3);
    const int kb = 64 * n0 + 16 * b + sp;
    zw[PADZ(kb      )] = o0;
    zw[PADZ(kb + 256)] = o1;
    zw[PADZ(kb + 512)] = o2;
    zw[PADZ(kb + 768)] = o3;
  }
  FENCE();
}

// untangle rfft2048 from packed Z, writing results IN PLACE into zw[slot].x:
// MODE 0: M[i]=|X[i]| ; MODE 1: P[i]=|X[i]|^2 ; MODE 2: R[k]=Re X[k] (k 1..511),
// R[512]=0.  Slot map: value index i lives at zw[PADZ(i)].x (i=1024 -> slot 1088).
// WAR-safe: iteration c reads slots {k=l+64c} (monotone up) and {1024-k>=513}
// (monotone down); writes of iter c hit slots <= 64c+63 and >= 1024-64c-63,
// both strictly outside all later reads. Same-lane same-slot is DS-in-order.
template<int MODE>
__device__ __forceinline__ void untangle(float2* __restrict__ zw,
                                         const int l,
                                         const float2* __restrict__ guw) {
  #pragma unroll
  for (int c = 0; c < 8; ++c) {
    const int k = l + 64 * c;                 // 0..511
    const int m = (1024 - k) & 1023;
    const float2 Zk = zw[PADZ(k)];
    const float2 Zm = zw[PADZ(m)];
    const float Er = 0.5f * (Zk.x + Zm.x), Ei = 0.5f * (Zk.y - Zm.y);
    const float Or = 0.5f * (Zk.y + Zm.y), Oi = 0.5f * (Zm.x - Zk.x);
    const float2 w = guw[k];
    const float wOr = w.x * Or - w.y * Oi;
    const float wOi = w.x * Oi + w.y * Or;
    if (MODE == 2) {
      if (k >= 1) zw[PADZ(k)].x = Er + wOr;
    } else {
      const float Xr = Er + wOr, Xi =  Ei + wOi;
      const float Yr = Er - wOr, Yi = -Ei + wOi;
      if (MODE == 0) {
        zw[PADZ(k)].x        = sqrtf(Xr * Xr + Xi * Xi);
        zw[PADZ(1024 - k)].x = sqrtf(Yr * Yr + Yi * Yi);
      } else {
        zw[PADZ(k)].x        = Xr * Xr + Xi * Xi;
        zw[PADZ(1024 - k)].x = Yr * Yr + Yi * Yi;
      }
    }
  }
  if (l == 0) {            // bin 512: |X[512]| = |Z[512]| ; R[512] masked to 0
    const float2 Z5 = zw[PADZ(512)];
    if (MODE == 0)      zw[PADZ(512)].x = sqrtf(Z5.x * Z5.x + Z5.y * Z5.y);
    else if (MODE == 1) zw[PADZ(512)].x = Z5.x * Z5.x + Z5.y * Z5.y;
    else                zw[PADZ(512)].x = 0.0f;
  }
}

// Fused: one WAVE per frame; fused median-of-5 via last-block pattern.
__global__ __launch_bounds__(256, 4) void pitch_main(const float* __restrict__ audio,
    int N, int T, float* __restrict__ f0, float* __restrict__ out,
    const float* __restrict__ gwin, const float2* __restrict__ gtwA,
    const float2* __restrict__ guw, unsigned* __restrict__ cnt) {
  __shared__ float2 zbuf[4][1092];     // per-wave workspace (max slot 1088)
  __shared__ int lastFlag;
  const int wv = threadIdx.x >> 6;
  const int l  = threadIdx.x & 63;
  const int frame = blockIdx.x * 4 + wv;
  const bool active = frame < T;

  if (active) {
    float2* zw = zbuf[wv];
    float2  v[16];

    // ---- pass 1: window + pack x[i] = a[2i] w[2i] + j a[2i+1] w[2i+1] ----
    const int base = frame * HOP - 1024;
    if (base >= 0 && base + 2048 <= N) {
      const float2* au2 = (const float2*)(audio + base);
      const float2* wi2 = (const float2*)gwin;
      #pragma unroll
      for (int j = 0; j < 16; ++j) {
        const float2 a = au2[l + 64 * j];
        const float2 w = wi2[l + 64 * j];
        v[j] = make_float2(a.x * w.x, a.y * w.y);
      }
    } else {                                   // 8 edge frames: reflect pad
      #pragma unroll
      for (int j = 0; j < 16; ++j) {
        const int i2 = 2 * (l + 64 * j);
        int j0 = base + i2, j1 = base + i2 + 1;
        j0 = (j0 < 0) ? -j0 : j0; j0 = (j0 >= N) ? (2 * N - 2 - j0) : j0;
        j1 = (j1 < 0) ? -j1 : j1; j1 = (j1 >= N) ? (2 * N - 2 - j1) : j1;
        v[j] = make_float2(audio[j0] * gwin[i2], audio[j1] * gwin[i2 + 1]);
      }
    }
    wave_fft1024(zw, v, l, gtwA);
    untangle<0>(zw, l, guw);                   // M[i] in zw[PADZ(i)].x
    FENCE();

    // ---- pass 2: pack z2[i] = M[2i] + j M[2i+1] (M == 0 past 1024) ----
    #pragma unroll
    for (int j = 0; j < 8; ++j) {
      const int i = l + 64 * j;                // 0..511
      v[j] = make_float2(zw[PADZ(2 * i)].x, zw[PADZ(2 * i + 1)].x);
    }
    {
      const float mv = zw[1088].x;             // M[1024], broadcast read
      v[8] = make_float2((l == 0) ? mv : 0.0f, 0.0f);
      #pragma unroll
      for (int j = 9; j < 16; ++j) v[j] = make_float2(0.0f, 0.0f);
    }
    wave_fft1024(zw, v, l, gtwA);
    untangle<1>(zw, l, guw);                   // P[i] in zw[PADZ(i)].x
    FENCE();

    // ---- pass 3: pack z3[i] = Pe[2i] + j Pe[2i+1], Pe = even extension ----
    #pragma unroll
    for (int j = 0; j < 8; ++j) {
      const int i = l + 64 * j;                // direct half, i <= 511
      v[j] = make_float2(zw[PADZ(2 * i)].x, zw[PADZ(2 * i + 1)].x);
    }
    #pragma unroll
    for (int j = 8; j < 16; ++j) {             // mirrored half, i >= 512
      const int i  = l + 64 * j;
      const int e0 = 2048 - 2 * i;             // 2..1024 (i=512 -> P[1024])
      v[j] = make_float2(zw[PADZ(e0)].x, zw[PADZ(e0 - 1)].x);
    }
    wave_fft1024(zw, v, l, gtwA);
    untangle<2>(zw, l, guw);                   // R[k] in zw[PADZ(k)].x
    FENCE();

    // ---- peak detect: any k in [2,511] with R[k] > R[k-1] && R[k] > R[k+1]
    int cond = 0;
    #pragma unroll
    for (int c = 0; c < 8; ++c) {
      const int k = l + 64 * c;
      if (k >= 2) {
        const float c0 = zw[PADZ(k)].x;
        if (c0 > zw[PADZ(k - 1)].x && c0 > zw[PADZ(k + 1)].x) cond = 1;
      }
    }
    const int has = __any(cond);
    if (l == 0)
      __hip_atomic_store(&f0[frame], has ? 50.0f : 0.0f,
                         __ATOMIC_RELAXED, __HIP_MEMORY_SCOPE_AGENT);
  }

  // ---- last-block fused median-of-5 (edge clamp) ----
  // hipcc drains vmcnt(0) before s_barrier, so all agent-scope f0 stores are
  // at the device coherence point before the counter increment below.
  __syncthreads();
  if (threadIdx.x == 0) {
    const unsigned old = __hip_atomic_fetch_add(cnt, 1u, __ATOMIC_ACQ_REL,
                                                __HIP_MEMORY_SCOPE_AGENT);
    lastFlag = (old == (unsigned)(gridDim.x - 1)) ? 1 : 0;
  }
  __syncthreads();
  if (lastFlag) {
    float* fsh = (float*)&zbuf[0][0];          // 8736 floats >= T+4
    for (int t0 = threadIdx.x; t0 < T; t0 += 256)
      fsh[t0 + 2] = __hip_atomic_load(&f0[t0], __ATOMIC_RELAXED,
                                      __HIP_MEMORY_SCOPE_AGENT);
    __syncthreads();
    if (threadIdx.x == 0) {
      fsh[0] = fsh[1] = fsh[2];
      fsh[T + 2] = fsh[T + 3] = fsh[T + 1];
    }
    __syncthreads();
    for (int t0 = threadIdx.x; t0 < T; t0 += 256) {
      float v0 = fsh[t0], v1 = fsh[t0 + 1], v2 = fsh[t0 + 2],
            v3 = fsh[t0 + 3], v4 = fsh[t0 + 4];
      #define SW(a,b) { const float lo = fminf(a, b); const float hi = fmaxf(a, b); a = lo; b = hi; }
      SW(v0,v1); SW(v3,v4); SW(v2,v4); SW(v2,v3); SW(v1,v4);
      SW(v0,v3); SW(v0,v2); SW(v1,v3); SW(v1,v2);
      #undef SW
      out[t0] = v2;
    }
  }
}

extern "C" void kernel_launch(void* const* d_in, const int* in_sizes, int n_in,
                              void* d_out, int out_size, void* d_ws, size_t ws_size,
                              hipStream_t stream) {
  const float* audio = (const float*)d_in[0];
  const int n = in_sizes[0];          // 2097152
  const int T = n / HOP + 1;          // 8193

  float* ws    = (float*)d_ws;
  float* f0    = ws;                  // [0, 8193)
  float* win   = ws + 8200;           // 2048 floats, 16B-aligned
  float2* gtwA = (float2*)(ws + 10248); // 1024 float2
  float2* guw  = (float2*)(ws + 12296); // 513 float2
  unsigned* cnt = (unsigned*)(ws + 13322);

  precompute<<<8, 256, 0, stream>>>(win, gtwA, guw, cnt);
  pitch_main<<<(T + 3) / 4, 256, 0, stream>>>(audio, n, T, f0, (float*)d_out,
                                              win, gtwA, guw, cnt);
}

// Round 8
// 239.666 us; speedup vs baseline: 1.2438x; 1.2438x over previous
//
#include <hip/hip_runtime.h>
#include <math.h>

#define HOP 256
#define PI2F 6.28318530717958647692f
#define PADZ(i) ((i) + ((i) >> 4))

#define C16 0.92387953251128675613f   // cos(pi/8)
#define S16 0.38268343236508977173f   // sin(pi/8)
#define RH  0.70710678118654752440f   // sqrt(2)/2

// wave-internal LDS ordering fence: drain LDS queue, pin scheduler.
#define FENCE() do { asm volatile("s_waitcnt lgkmcnt(0)" ::: "memory"); \
                     __builtin_amdgcn_sched_barrier(0); } while (0)

// ---------------- one-time tables (recomputed every launch into d_ws) --------
// win[2048]: periodic Hann
// gtwA[1024]: gtwA[64*s + l] = e^{-j2pi*l*s/1024}, l in [0,64), s in [0,16)
//             (also serves stage B: w64^{n0*u} = gtwA[64*u + 16*n0])
// guw[513]:  e^{-j2pi*k/2048} untangle twiddles
// cnt: zeroed completion counter for the fused-median last-block pattern
__global__ __launch_bounds__(256) void precompute(float* __restrict__ win,
                                                  float2* __restrict__ gtwA,
                                                  float2* __restrict__ guw,
                                                  unsigned* __restrict__ cnt) {
  const int i = blockIdx.x * blockDim.x + threadIdx.x;
  if (i < 2048) win[i] = 0.5f * (1.0f - cosf(PI2F * (float)i / 2048.0f));
  if (i < 1024) {
    const int s2 = i >> 6, l = i & 63;
    float s, c; sincosf(-PI2F * (float)(l * s2) / 1024.0f, &s, &c);
    gtwA[i] = make_float2(c, s);
  }
  if (i < 513) {
    float s, c; sincosf(-PI2F * (float)i / 2048.0f, &s, &c);
    guw[i] = make_float2(c, s);
  }
  if (i == 0) *cnt = 0u;
}

// ---------------- complex helpers (forward convention w16 = e^{-j2pi/16}) ----
__device__ __forceinline__ float2 cadd(float2 a, float2 b){ return make_float2(a.x+b.x, a.y+b.y); }
__device__ __forceinline__ float2 csub(float2 a, float2 b){ return make_float2(a.x-b.x, a.y-b.y); }
__device__ __forceinline__ float2 cmul(float2 a, float2 b){
  return make_float2(fmaf(a.x, b.x, -a.y*b.y), fmaf(a.x, b.y, a.y*b.x));
}
__device__ __forceinline__ float2 mul_mj(float2 v){ return make_float2(v.y, -v.x); }  // *(-j)
__device__ __forceinline__ float2 mul_pj(float2 v){ return make_float2(-v.y, v.x); }  // *(+j)
// multiply by w16^e
__device__ __forceinline__ float2 tw1f(float2 v){ return make_float2(fmaf(C16,v.x, S16*v.y), fmaf(C16,v.y,-S16*v.x)); }
__device__ __forceinline__ float2 tw2f(float2 v){ return make_float2(RH*(v.x+v.y), RH*(v.y-v.x)); }
__device__ __forceinline__ float2 tw3f(float2 v){ return make_float2(fmaf(S16,v.x, C16*v.y), fmaf(S16,v.y,-C16*v.x)); }
__device__ __forceinline__ float2 tw4f(float2 v){ return make_float2(v.y, -v.x); }
__device__ __forceinline__ float2 tw6f(float2 v){ return make_float2(RH*(v.y-v.x), -RH*(v.x+v.y)); }
__device__ __forceinline__ float2 tw9f(float2 v){ return make_float2(fmaf(-C16,v.x,-S16*v.y), fmaf(S16,v.x,-C16*v.y)); }

__device__ __forceinline__ void dft4(float2 a, float2 b, float2 c, float2 d,
                                     float2& o0, float2& o1, float2& o2, float2& o3) {
  const float2 t0 = cadd(a, c), t1 = csub(a, c);
  const float2 t2 = cadd(b, d), t3 = csub(b, d);
  o0 = cadd(t0, t2);
  o2 = csub(t0, t2);
  o1 = cadd(t1, mul_mj(t3));
  o3 = cadd(t1, mul_pj(t3));
}

// in-place 16-pt DFT: v[k] = sum_j v_in[j] * w16^{jk}
__device__ __forceinline__ void dft16(float2 v[16]) {
  float2 A0[4], A1[4], A2[4], A3[4];
  dft4(v[0], v[4], v[ 8], v[12], A0[0], A0[1], A0[2], A0[3]);
  dft4(v[1], v[5], v[ 9], v[13], A1[0], A1[1], A1[2], A1[3]);
  dft4(v[2], v[6], v[10], v[14], A2[0], A2[1], A2[2], A2[3]);
  dft4(v[3], v[7], v[11], v[15], A3[0], A3[1], A3[2], A3[3]);
  dft4(A0[0],       A1[0],        A2[0],        A3[0],       v[0], v[4], v[ 8], v[12]);
  dft4(A0[1], tw1f(A1[1]), tw2f(A2[1]), tw3f(A3[1]), v[1], v[5], v[ 9], v[13]);
  dft4(A0[2], tw2f(A1[2]), tw4f(A2[2]), tw6f(A3[2]), v[2], v[6], v[10], v[14]);
  dft4(A0[3], tw3f(A1[3]), tw6f(A2[3]), tw9f(A3[3]), v[3], v[7], v[11], v[15]);
}

// 1024-pt FFT for ONE wave: input v[j] = x[l + 64 j]; output natural-order Z in
// zw[PADZ(k)]. Decomposition 1024 = 16 x 16 x 4, two LDS exchanges.
// Stage twiddles from the precomputed global table (coalesced, L1-hot).
__device__ __forceinline__ void wave_fft1024(float2* __restrict__ zw, float2 v[16],
                                             const int l,
                                             const float2* __restrict__ gtwA) {
  // stage A: z_s[l] = w1024^{l s} * sum_j x[l+64j] w16^{js}
  dft16(v);
  #pragma unroll
  for (int s = 1; s < 16; ++s) v[s] = cmul(v[s], gtwA[(s << 6) + l]);
  // exchange 1: E[s][l] at 65 s + l
  #pragma unroll
  for (int s = 0; s < 16; ++s) zw[65 * s + l] = v[s];
  FENCE();
  const int sp = l >> 2, n0 = l & 3;
  #pragma unroll
  for (int r = 0; r < 16; ++r) v[r] = zw[65 * sp + n0 + 4 * r];
  // stage B: g_u = w64^{n0 u} * sum_r z_sp[n0+4r] w16^{ru}
  dft16(v);
  #pragma unroll
  for (int u = 1; u < 16; ++u) v[u] = cmul(v[u], gtwA[(u << 6) + (n0 << 4)]);
  // exchange 2: E2[sp][u][n0] at 65 sp + 4u + n0
  #pragma unroll
  for (int u = 0; u < 16; ++u) zw[65 * sp + 4 * u + n0] = v[u];
  FENCE();
  #pragma unroll
  for (int b = 0; b < 4; ++b)
    #pragma unroll
    for (int m0 = 0; m0 < 4; ++m0)
      v[4 * b + m0] = zw[65 * sp + 16 * n0 + 4 * b + m0];
  FENCE();   // all reads retired before stores overwrite the buffer
  // final radix-4: Z[256 q2 + 64 n0 + 16 b + sp]
  #pragma unroll
  for (int b = 0; b < 4; ++b) {
    float2 o0, o1, o2, o3;
    dft4(v[4*b+0], v[4*b+1], v[4*b+2], v[4*b+3], o0, o1, o2, o3);
    const int kb = 64 * n0 + 16 * b + sp;
    zw[PADZ(kb      )] = o0;
    zw[PADZ(kb + 256)] = o1;
    zw[PADZ(kb + 512)] = o2;
    zw[PADZ(kb + 768)] = o3;
  }
  FENCE();
}

// untangle rfft2048 from packed Z, writing results IN PLACE into zw[slot].x:
// MODE 0: M[i]=|X[i]| ; MODE 1: P[i]=|X[i]|^2 ; MODE 2: R[k]=Re X[k] (k 1..511),
// R[512]=0.  Slot map: value index i lives at zw[PADZ(i)].x (i=1024 -> slot 1088).
// WAR-safe: iteration c reads slots {k=l+64c} (monotone up) and {1024-k>=513}
// (monotone down); writes of iter c hit slots <= 64c+63 and >= 1024-64c-63,
// both strictly outside all later reads. Same-lane same-slot is DS-in-order.
template<int MODE>
__device__ __forceinline__ void untangle(float2* __restrict__ zw,
                                         const int l,
                                         const float2* __restrict__ guw) {
  #pragma unroll
  for (int c = 0; c < 8; ++c) {
    const int k = l + 64 * c;                 // 0..511
    const int m = (1024 - k) & 1023;
    const float2 Zk = zw[PADZ(k)];
    const float2 Zm = zw[PADZ(m)];
    const float Er = 0.5f * (Zk.x + Zm.x), Ei = 0.5f * (Zk.y - Zm.y);
    const float Or = 0.5f * (Zk.y + Zm.y), Oi = 0.5f * (Zm.x - Zk.x);
    const float2 w = guw[k];
    const float wOr = w.x * Or - w.y * Oi;
    const float wOi = w.x * Oi + w.y * Or;
    if (MODE == 2) {
      if (k >= 1) zw[PADZ(k)].x = Er + wOr;
    } else {
      const float Xr = Er + wOr, Xi =  Ei + wOi;
      const float Yr = Er - wOr, Yi = -Ei + wOi;
      if (MODE == 0) {
        zw[PADZ(k)].x        = sqrtf(Xr * Xr + Xi * Xi);
        zw[PADZ(1024 - k)].x = sqrtf(Yr * Yr + Yi * Yi);
      } else {
        zw[PADZ(k)].x        = Xr * Xr + Xi * Xi;
        zw[PADZ(1024 - k)].x = Yr * Yr + Yi * Yi;
      }
    }
  }
  if (l == 0) {            // bin 512: |X[512]| = |Z[512]| ; R[512] masked to 0
    const float2 Z5 = zw[PADZ(512)];
    if (MODE == 0)      zw[PADZ(512)].x = sqrtf(Z5.x * Z5.x + Z5.y * Z5.y);
    else if (MODE == 1) zw[PADZ(512)].x = Z5.x * Z5.x + Z5.y * Z5.y;
    else                zw[PADZ(512)].x = 0.0f;
  }
}

// Fused: one WAVE per frame; fused median-of-5 via last-block pattern.
// launch_bounds (256,3): proven no-spill allocation (round 6: 72 VGPR).
// (256,4) made the allocator target 64 VGPR and spill v[16] to scratch
// (round 7: 86 MB scratch writes, 3.6x regression).
__global__ __launch_bounds__(256, 3) void pitch_main(const float* __restrict__ audio,
    int N, int T, float* __restrict__ f0, float* __restrict__ out,
    const float* __restrict__ gwin, const float2* __restrict__ gtwA,
    const float2* __restrict__ guw, unsigned* __restrict__ cnt) {
  __shared__ float2 zbuf[4][1092];     // per-wave workspace (max slot 1088)
  __shared__ int lastFlag;
  const int wv = threadIdx.x >> 6;
  const int l  = threadIdx.x & 63;
  const int frame = blockIdx.x * 4 + wv;
  const bool active = frame < T;

  if (active) {
    float2* zw = zbuf[wv];
    float2  v[16];

    // ---- pass 1: window + pack x[i] = a[2i] w[2i] + j a[2i+1] w[2i+1] ----
    const int base = frame * HOP - 1024;
    if (base >= 0 && base + 2048 <= N) {
      const float2* au2 = (const float2*)(audio + base);
      const float2* wi2 = (const float2*)gwin;
      #pragma unroll
      for (int j = 0; j < 16; ++j) {
        const float2 a = au2[l + 64 * j];
        const float2 w = wi2[l + 64 * j];
        v[j] = make_float2(a.x * w.x, a.y * w.y);
      }
    } else {                                   // 8 edge frames: reflect pad
      #pragma unroll
      for (int j = 0; j < 16; ++j) {
        const int i2 = 2 * (l + 64 * j);
        int j0 = base + i2, j1 = base + i2 + 1;
        j0 = (j0 < 0) ? -j0 : j0; j0 = (j0 >= N) ? (2 * N - 2 - j0) : j0;
        j1 = (j1 < 0) ? -j1 : j1; j1 = (j1 >= N) ? (2 * N - 2 - j1) : j1;
        v[j] = make_float2(audio[j0] * gwin[i2], audio[j1] * gwin[i2 + 1]);
      }
    }
    wave_fft1024(zw, v, l, gtwA);
    untangle<0>(zw, l, guw);                   // M[i] in zw[PADZ(i)].x
    FENCE();

    // ---- pass 2: pack z2[i] = M[2i] + j M[2i+1] (M == 0 past 1024) ----
    #pragma unroll
    for (int j = 0; j < 8; ++j) {
      const int i = l + 64 * j;                // 0..511
      v[j] = make_float2(zw[PADZ(2 * i)].x, zw[PADZ(2 * i + 1)].x);
    }
    {
      const float mv = zw[1088].x;             // M[1024], broadcast read
      v[8] = make_float2((l == 0) ? mv : 0.0f, 0.0f);
      #pragma unroll
      for (int j = 9; j < 16; ++j) v[j] = make_float2(0.0f, 0.0f);
    }
    wave_fft1024(zw, v, l, gtwA);
    untangle<1>(zw, l, guw);                   // P[i] in zw[PADZ(i)].x
    FENCE();

    // ---- pass 3: pack z3[i] = Pe[2i] + j Pe[2i+1], Pe = even extension ----
    #pragma unroll
    for (int j = 0; j < 8; ++j) {
      const int i = l + 64 * j;                // direct half, i <= 511
      v[j] = make_float2(zw[PADZ(2 * i)].x, zw[PADZ(2 * i + 1)].x);
    }
    #pragma unroll
    for (int j = 8; j < 16; ++j) {             // mirrored half, i >= 512
      const int i  = l + 64 * j;
      const int e0 = 2048 - 2 * i;             // 2..1024 (i=512 -> P[1024])
      v[j] = make_float2(zw[PADZ(e0)].x, zw[PADZ(e0 - 1)].x);
    }
    wave_fft1024(zw, v, l, gtwA);
    untangle<2>(zw, l, guw);                   // R[k] in zw[PADZ(k)].x
    FENCE();

    // ---- peak detect: any k in [2,511] with R[k] > R[k-1] && R[k] > R[k+1]
    int cond = 0;
    #pragma unroll
    for (int c = 0; c < 8; ++c) {
      const int k = l + 64 * c;
      if (k >= 2) {
        const float c0 = zw[PADZ(k)].x;
        if (c0 > zw[PADZ(k - 1)].x && c0 > zw[PADZ(k + 1)].x) cond = 1;
      }
    }
    const int has = __any(cond);
    if (l == 0)
      __hip_atomic_store(&f0[frame], has ? 50.0f : 0.0f,
                         __ATOMIC_RELAXED, __HIP_MEMORY_SCOPE_AGENT);
  }

  // ---- last-block fused median-of-5 (edge clamp) ----
  // hipcc drains vmcnt(0) before s_barrier, so all agent-scope f0 stores are
  // at the device coherence point before the counter increment below.
  __syncthreads();
  if (threadIdx.x == 0) {
    const unsigned old = __hip_atomic_fetch_add(cnt, 1u, __ATOMIC_ACQ_REL,
                                                __HIP_MEMORY_SCOPE_AGENT);
    lastFlag = (old == (unsigned)(gridDim.x - 1)) ? 1 : 0;
  }
  __syncthreads();
  if (lastFlag) {
    float* fsh = (float*)&zbuf[0][0];          // 8736 floats >= T+4
    for (int t0 = threadIdx.x; t0 < T; t0 += 256)
      fsh[t0 + 2] = __hip_atomic_load(&f0[t0], __ATOMIC_RELAXED,
                                      __HIP_MEMORY_SCOPE_AGENT);
    __syncthreads();
    if (threadIdx.x == 0) {
      fsh[0] = fsh[1] = fsh[2];
      fsh[T + 2] = fsh[T + 3] = fsh[T + 1];
    }
    __syncthreads();
    for (int t0 = threadIdx.x; t0 < T; t0 += 256) {
      float v0 = fsh[t0], v1 = fsh[t0 + 1], v2 = fsh[t0 + 2],
            v3 = fsh[t0 + 3], v4 = fsh[t0 + 4];
      #define SW(a,b) { const float lo = fminf(a, b); const float hi = fmaxf(a, b); a = lo; b = hi; }
      SW(v0,v1); SW(v3,v4); SW(v2,v4); SW(v2,v3); SW(v1,v4);
      SW(v0,v3); SW(v0,v2); SW(v1,v3); SW(v1,v2);
      #undef SW
      out[t0] = v2;
    }
  }
}

extern "C" void kernel_launch(void* const* d_in, const int* in_sizes, int n_in,
                              void* d_out, int out_size, void* d_ws, size_t ws_size,
                              hipStream_t stream) {
  const float* audio = (const float*)d_in[0];
  const int n = in_sizes[0];          // 2097152
  const int T = n / HOP + 1;          // 8193

  float* ws    = (float*)d_ws;
  float* f0    = ws;                  // [0, 8193)
  float* win   = ws + 8200;           // 2048 floats, 16B-aligned
  float2* gtwA = (float2*)(ws + 10248); // 1024 float2
  float2* guw  = (float2*)(ws + 12296); // 513 float2
  unsigned* cnt = (unsigned*)(ws + 13322);

  precompute<<<8, 256, 0, stream>>>(win, gtwA, guw, cnt);
  pitch_main<<<(T + 3) / 4, 256, 0, stream>>>(audio, n, T, f0, (float*)d_out,
                                              win, gtwA, guw, cnt);
}

// Round 9
// 145.051 us; speedup vs baseline: 2.0551x; 1.6523x over previous
//
#include <hip/hip_runtime.h>
#include <math.h>

#define HOP 256
#define PI2F 6.28318530717958647692f
#define PADZ(i) ((i) + ((i) >> 4))

#define C16 0.92387953251128675613f   // cos(pi/8)
#define S16 0.38268343236508977173f   // sin(pi/8)
#define RH  0.70710678118654752440f   // sqrt(2)/2

// wave-internal LDS ordering fence: drain LDS queue, pin scheduler.
#define FENCE() do { asm volatile("s_waitcnt lgkmcnt(0)" ::: "memory"); \
                     __builtin_amdgcn_sched_barrier(0); } while (0)

// ---------------- one-time tables (recomputed every launch into d_ws) --------
// win[2048]: periodic Hann
// gtwA[1024]: gtwA[64*s + l] = e^{-j2pi*l*s/1024}  (also serves stage B)
// guw[513]:  e^{-j2pi*k/2048} untangle twiddles
__global__ __launch_bounds__(256) void precompute(float* __restrict__ win,
                                                  float2* __restrict__ gtwA,
                                                  float2* __restrict__ guw) {
  const int i = blockIdx.x * blockDim.x + threadIdx.x;
  if (i < 2048) win[i] = 0.5f * (1.0f - cosf(PI2F * (float)i / 2048.0f));
  if (i < 1024) {
    const int s2 = i >> 6, l = i & 63;
    float s, c; sincosf(-PI2F * (float)(l * s2) / 1024.0f, &s, &c);
    gtwA[i] = make_float2(c, s);
  }
  if (i < 513) {
    float s, c; sincosf(-PI2F * (float)i / 2048.0f, &s, &c);
    guw[i] = make_float2(c, s);
  }
}

// ---------------- complex helpers (forward convention w16 = e^{-j2pi/16}) ----
__device__ __forceinline__ float2 cadd(float2 a, float2 b){ return make_float2(a.x+b.x, a.y+b.y); }
__device__ __forceinline__ float2 csub(float2 a, float2 b){ return make_float2(a.x-b.x, a.y-b.y); }
__device__ __forceinline__ float2 cmul(float2 a, float2 b){
  return make_float2(fmaf(a.x, b.x, -a.y*b.y), fmaf(a.x, b.y, a.y*b.x));
}
__device__ __forceinline__ float2 mul_mj(float2 v){ return make_float2(v.y, -v.x); }  // *(-j)
__device__ __forceinline__ float2 mul_pj(float2 v){ return make_float2(-v.y, v.x); }  // *(+j)
// multiply by w16^e
__device__ __forceinline__ float2 tw1f(float2 v){ return make_float2(fmaf(C16,v.x, S16*v.y), fmaf(C16,v.y,-S16*v.x)); }
__device__ __forceinline__ float2 tw2f(float2 v){ return make_float2(RH*(v.x+v.y), RH*(v.y-v.x)); }
__device__ __forceinline__ float2 tw3f(float2 v){ return make_float2(fmaf(S16,v.x, C16*v.y), fmaf(S16,v.y,-C16*v.x)); }
__device__ __forceinline__ float2 tw6f(float2 v){ return make_float2(RH*(v.y-v.x), -RH*(v.x+v.y)); }
__device__ __forceinline__ float2 tw9f(float2 v){ return make_float2(fmaf(-C16,v.x,-S16*v.y), fmaf(S16,v.x,-C16*v.y)); }

__device__ __forceinline__ void dft4(float2 a, float2 b, float2 c, float2 d,
                                     float2& o0, float2& o1, float2& o2, float2& o3) {
  const float2 t0 = cadd(a, c), t1 = csub(a, c);
  const float2 t2 = cadd(b, d), t3 = csub(b, d);
  o0 = cadd(t0, t2);
  o2 = csub(t0, t2);
  o1 = cadd(t1, mul_mj(t3));
  o3 = cadd(t1, mul_pj(t3));
}

// in-place 16-pt DFT: v[k] = sum_j v_in[j] * w16^{jk}
__device__ __forceinline__ void dft16(float2 v[16]) {
  float2 A0[4], A1[4], A2[4], A3[4];
  dft4(v[0], v[4], v[ 8], v[12], A0[0], A0[1], A0[2], A0[3]);
  dft4(v[1], v[5], v[ 9], v[13], A1[0], A1[1], A1[2], A1[3]);
  dft4(v[2], v[6], v[10], v[14], A2[0], A2[1], A2[2], A2[3]);
  dft4(v[3], v[7], v[11], v[15], A3[0], A3[1], A3[2], A3[3]);
  dft4(A0[0],       A1[0],        A2[0],        A3[0],       v[0], v[4], v[ 8], v[12]);
  dft4(A0[1], tw1f(A1[1]), tw2f(A2[1]), tw3f(A3[1]), v[1], v[5], v[ 9], v[13]);
  dft4(A0[2], tw2f(A1[2]), mul_mj(A2[2]), tw6f(A3[2]), v[2], v[6], v[10], v[14]);
  dft4(A0[3], tw3f(A1[3]), tw6f(A2[3]), tw9f(A3[3]), v[3], v[7], v[11], v[15]);
}

// 1024-pt FFT for ONE wave: input v[j] = x[l + 64 j]; output natural-order Z in
// zw[PADZ(k)]. Decomposition 1024 = 16 x 16 x 4, two LDS exchanges.
__device__ __forceinline__ void wave_fft1024(float2* __restrict__ zw, float2 v[16],
                                             const int l,
                                             const float2* __restrict__ gtwA) {
  // stage A: z_s[l] = w1024^{l s} * sum_j x[l+64j] w16^{js}
  dft16(v);
  #pragma unroll
  for (int s = 1; s < 16; ++s) v[s] = cmul(v[s], gtwA[(s << 6) + l]);
  // exchange 1: E[s][l] at 65 s + l
  #pragma unroll
  for (int s = 0; s < 16; ++s) zw[65 * s + l] = v[s];
  FENCE();
  const int sp = l >> 2, n0 = l & 3;
  #pragma unroll
  for (int r = 0; r < 16; ++r) v[r] = zw[65 * sp + n0 + 4 * r];
  // stage B: g_u = w64^{n0 u} * sum_r z_sp[n0+4r] w16^{ru}
  dft16(v);
  #pragma unroll
  for (int u = 1; u < 16; ++u) v[u] = cmul(v[u], gtwA[(u << 6) + (n0 << 4)]);
  // exchange 2: E2[sp][u][n0] at 65 sp + 4u + n0
  #pragma unroll
  for (int u = 0; u < 16; ++u) zw[65 * sp + 4 * u + n0] = v[u];
  FENCE();
  #pragma unroll
  for (int b = 0; b < 4; ++b)
    #pragma unroll
    for (int m0 = 0; m0 < 4; ++m0)
      v[4 * b + m0] = zw[65 * sp + 16 * n0 + 4 * b + m0];
  FENCE();   // all reads retired before stores overwrite the buffer
  // final radix-4: Z[256 q2 + 64 n0 + 16 b + sp]
  #pragma unroll
  for (int b = 0; b < 4; ++b) {
    float2 o0, o1, o2, o3;
    dft4(v[4*b+0], v[4*b+1], v[4*b+2], v[4*b+3], o0, o1, o2, o3);
    const int kb = 64 * n0 + 16 * b + sp;
    zw[PADZ(kb      )] = o0;
    zw[PADZ(kb + 256)] = o1;
    zw[PADZ(kb + 512)] = o2;
    zw[PADZ(kb + 768)] = o3;
  }
  FENCE();
}

// untangle rfft2048 from packed Z, writing results IN PLACE into zw[slot].x:
// MODE 0: M[i]=|X[i]| ; MODE 1: P[i]=|X[i]|^2 ; MODE 2: R[k]=Re X[k] (k 1..511),
// R[512]=0.  Slot map: value index i lives at zw[PADZ(i)].x (i=1024 -> slot 1088).
// WAR-safe: iteration c reads slots {k=l+64c} (monotone up) and {1024-k>=513}
// (monotone down); writes of iter c hit slots <= 64c+63 and >= 1024-64c-63,
// both strictly outside all later reads. Same-lane same-slot is DS-in-order.
template<int MODE>
__device__ __forceinline__ void untangle(float2* __restrict__ zw,
                                         const int l,
                                         const float2* __restrict__ guw) {
  #pragma unroll
  for (int c = 0; c < 8; ++c) {
    const int k = l + 64 * c;                 // 0..511
    const int m = (1024 - k) & 1023;
    const float2 Zk = zw[PADZ(k)];
    const float2 Zm = zw[PADZ(m)];
    const float Er = 0.5f * (Zk.x + Zm.x), Ei = 0.5f * (Zk.y - Zm.y);
    const float Or = 0.5f * (Zk.y + Zm.y), Oi = 0.5f * (Zm.x - Zk.x);
    const float2 w = guw[k];
    const float wOr = w.x * Or - w.y * Oi;
    const float wOi = w.x * Oi + w.y * Or;
    if (MODE == 2) {
      if (k >= 1) zw[PADZ(k)].x = Er + wOr;
    } else {
      const float Xr = Er + wOr, Xi =  Ei + wOi;
      const float Yr = Er - wOr, Yi = -Ei + wOi;
      if (MODE == 0) {
        zw[PADZ(k)].x        = sqrtf(Xr * Xr + Xi * Xi);
        zw[PADZ(1024 - k)].x = sqrtf(Yr * Yr + Yi * Yi);
      } else {
        zw[PADZ(k)].x        = Xr * Xr + Xi * Xi;
        zw[PADZ(1024 - k)].x = Yr * Yr + Yi * Yi;
      }
    }
  }
  if (l == 0) {            // bin 512: |X[512]| = |Z[512]| ; R[512] masked to 0
    const float2 Z5 = zw[PADZ(512)];
    if (MODE == 0)      zw[PADZ(512)].x = sqrtf(Z5.x * Z5.x + Z5.y * Z5.y);
    else if (MODE == 1) zw[PADZ(512)].x = Z5.x * Z5.x + Z5.y * Z5.y;
    else                zw[PADZ(512)].x = 0.0f;
  }
}

// Fused: one WAVE per frame; plain f0 stores; median is a separate kernel
// (round 8 lesson: per-block agent-scope ACQ_REL atomics forced L2
// writeback/invalidate per block -> 16.7 MB HBM writes + latency stalls).
// launch_bounds (256,3): proven no-spill allocation (round 6: 72 VGPR).
__global__ __launch_bounds__(256, 3) void pitch_main(const float* __restrict__ audio,
    int N, int T, float* __restrict__ f0,
    const float* __restrict__ gwin, const float2* __restrict__ gtwA,
    const float2* __restrict__ guw) {
  __shared__ float2 zbuf[4][1092];     // per-wave workspace (max slot 1088), 34.9 KB
  const int wv = threadIdx.x >> 6;
  const int l  = threadIdx.x & 63;
  const int frame = blockIdx.x * 4 + wv;
  if (frame >= T) return;
  float2* zw = zbuf[wv];
  float2  v[16];

  // ---- pass 1: window + pack x[i] = a[2i] w[2i] + j a[2i+1] w[2i+1] ----
  const int base = frame * HOP - 1024;
  if (base >= 0 && base + 2048 <= N) {
    const float2* au2 = (const float2*)(audio + base);
    const float2* wi2 = (const float2*)gwin;
    #pragma unroll
    for (int j = 0; j < 16; ++j) {
      const float2 a = au2[l + 64 * j];
      const float2 w = wi2[l + 64 * j];
      v[j] = make_float2(a.x * w.x, a.y * w.y);
    }
  } else {                                   // 8 edge frames: reflect pad
    #pragma unroll
    for (int j = 0; j < 16; ++j) {
      const int i2 = 2 * (l + 64 * j);
      int j0 = base + i2, j1 = base + i2 + 1;
      j0 = (j0 < 0) ? -j0 : j0; j0 = (j0 >= N) ? (2 * N - 2 - j0) : j0;
      j1 = (j1 < 0) ? -j1 : j1; j1 = (j1 >= N) ? (2 * N - 2 - j1) : j1;
      v[j] = make_float2(audio[j0] * gwin[i2], audio[j1] * gwin[i2 + 1]);
    }
  }
  wave_fft1024(zw, v, l, gtwA);
  untangle<0>(zw, l, guw);                   // M[i] in zw[PADZ(i)].x
  FENCE();

  // ---- pass 2: pack z2[i] = M[2i] + j M[2i+1] (M == 0 past 1024) ----
  #pragma unroll
  for (int j = 0; j < 8; ++j) {
    const int i = l + 64 * j;                // 0..511
    v[j] = make_float2(zw[PADZ(2 * i)].x, zw[PADZ(2 * i + 1)].x);
  }
  {
    const float mv = zw[1088].x;             // M[1024], broadcast read
    v[8] = make_float2((l == 0) ? mv : 0.0f, 0.0f);
    #pragma unroll
    for (int j = 9; j < 16; ++j) v[j] = make_float2(0.0f, 0.0f);
  }
  wave_fft1024(zw, v, l, gtwA);
  untangle<1>(zw, l, guw);                   // P[i] in zw[PADZ(i)].x
  FENCE();

  // ---- pass 3: pack z3[i] = Pe[2i] + j Pe[2i+1], Pe = even extension ----
  #pragma unroll
  for (int j = 0; j < 8; ++j) {
    const int i = l + 64 * j;                // direct half, i <= 511
    v[j] = make_float2(zw[PADZ(2 * i)].x, zw[PADZ(2 * i + 1)].x);
  }
  #pragma unroll
  for (int j = 8; j < 16; ++j) {             // mirrored half, i >= 512
    const int i  = l + 64 * j;
    const int e0 = 2048 - 2 * i;             // 2..1024 (i=512 -> P[1024])
    v[j] = make_float2(zw[PADZ(e0)].x, zw[PADZ(e0 - 1)].x);
  }
  wave_fft1024(zw, v, l, gtwA);
  untangle<2>(zw, l, guw);                   // R[k] in zw[PADZ(k)].x
  FENCE();

  // ---- peak detect: any k in [2,511] with R[k] > R[k-1] && R[k] > R[k+1]
  int cond = 0;
  #pragma unroll
  for (int c = 0; c < 8; ++c) {
    const int k = l + 64 * c;
    if (k >= 2) {
      const float c0 = zw[PADZ(k)].x;
      if (c0 > zw[PADZ(k - 1)].x && c0 > zw[PADZ(k + 1)].x) cond = 1;
    }
  }
  const int has = __any(cond);
  if (l == 0) f0[frame] = has ? 50.0f : 0.0f;
}

// Median-of-5 smoothing with edge clamp (jnp.pad mode='edge').
__global__ __launch_bounds__(256) void median5_kernel(const float* __restrict__ f0,
                                                      float* __restrict__ out, int T) {
  const int t = blockIdx.x * blockDim.x + threadIdx.x;
  if (t >= T) return;
  float v[5];
  #pragma unroll
  for (int m = 0; m < 5; ++m) {
    int idx = t + m - 2;
    idx = idx < 0 ? 0 : (idx > T - 1 ? T - 1 : idx);
    v[m] = f0[idx];
  }
  #define SW(a,b) { float lo = fminf(v[a], v[b]); float hi = fmaxf(v[a], v[b]); v[a] = lo; v[b] = hi; }
  SW(0,1); SW(3,4); SW(2,4); SW(2,3); SW(1,4); SW(0,3); SW(0,2); SW(1,3); SW(1,2);
  #undef SW
  out[t] = v[2];
}

extern "C" void kernel_launch(void* const* d_in, const int* in_sizes, int n_in,
                              void* d_out, int out_size, void* d_ws, size_t ws_size,
                              hipStream_t stream) {
  const float* audio = (const float*)d_in[0];
  const int n = in_sizes[0];          // 2097152
  const int T = n / HOP + 1;          // 8193

  float* ws    = (float*)d_ws;
  float* f0    = ws;                  // [0, 8193)
  float* win   = ws + 8200;           // 2048 floats, 16B-aligned
  float2* gtwA = (float2*)(ws + 10248); // 1024 float2
  float2* guw  = (float2*)(ws + 12296); // 513 float2

  precompute<<<8, 256, 0, stream>>>(win, gtwA, guw);
  pitch_main<<<(T + 3) / 4, 256, 0, stream>>>(audio, n, T, f0, win, gtwA, guw);
  median5_kernel<<<(T + 255) / 256, 256, 0, stream>>>(f0, (float*)d_out, T);
}

// Round 10
// 118.042 us; speedup vs baseline: 2.5253x; 1.2288x over previous
//
#include <hip/hip_runtime.h>
#include <math.h>

#define HOP 256
#define PI2F 6.28318530717958647692f
#define PADZ(i) ((i) + ((i) >> 4))

#define C16 0.92387953251128675613f   // cos(pi/8)
#define S16 0.38268343236508977173f   // sin(pi/8)
#define RH  0.70710678118654752440f   // sqrt(2)/2

// wave-internal LDS ordering fence: drain LDS queue, pin scheduler.
#define FENCE() do { asm volatile("s_waitcnt lgkmcnt(0)" ::: "memory"); \
                     __builtin_amdgcn_sched_barrier(0); } while (0)

// ---------------- one-time tables (recomputed every launch into d_ws) --------
// win[2048]: periodic Hann; gtw[512]: e^{-j2pi m/1024}; guw[513]: e^{-j2pi k/2048}
__global__ __launch_bounds__(256) void precompute(float* __restrict__ win,
                                                  float2* __restrict__ gtw,
                                                  float2* __restrict__ guw) {
  const int i = blockIdx.x * blockDim.x + threadIdx.x;
  if (i < 2048) win[i] = 0.5f * (1.0f - cosf(PI2F * (float)i / 2048.0f));
  if (i < 512) {
    float s, c; sincosf(-PI2F * (float)i / 1024.0f, &s, &c);
    gtw[i] = make_float2(c, s);
  }
  if (i < 513) {
    float s, c; sincosf(-PI2F * (float)i / 2048.0f, &s, &c);
    guw[i] = make_float2(c, s);
  }
}

// ---------------- complex helpers (forward convention w16 = e^{-j2pi/16}) ----
__device__ __forceinline__ float2 cadd(float2 a, float2 b){ return make_float2(a.x+b.x, a.y+b.y); }
__device__ __forceinline__ float2 csub(float2 a, float2 b){ return make_float2(a.x-b.x, a.y-b.y); }
__device__ __forceinline__ float2 cmul(float2 a, float2 b){
  return make_float2(fmaf(a.x, b.x, -a.y*b.y), fmaf(a.x, b.y, a.y*b.x));
}
__device__ __forceinline__ float2 mul_mj(float2 v){ return make_float2(v.y, -v.x); }  // *(-j)
__device__ __forceinline__ float2 mul_pj(float2 v){ return make_float2(-v.y, v.x); }  // *(+j)
// multiply by w16^e
__device__ __forceinline__ float2 tw1f(float2 v){ return make_float2(fmaf(C16,v.x, S16*v.y), fmaf(C16,v.y,-S16*v.x)); }
__device__ __forceinline__ float2 tw2f(float2 v){ return make_float2(RH*(v.x+v.y), RH*(v.y-v.x)); }
__device__ __forceinline__ float2 tw3f(float2 v){ return make_float2(fmaf(S16,v.x, C16*v.y), fmaf(S16,v.y,-C16*v.x)); }
__device__ __forceinline__ float2 tw6f(float2 v){ return make_float2(RH*(v.y-v.x), -RH*(v.x+v.y)); }
__device__ __forceinline__ float2 tw9f(float2 v){ return make_float2(fmaf(-C16,v.x,-S16*v.y), fmaf(S16,v.x,-C16*v.y)); }

__device__ __forceinline__ void dft4(float2 a, float2 b, float2 c, float2 d,
                                     float2& o0, float2& o1, float2& o2, float2& o3) {
  const float2 t0 = cadd(a, c), t1 = csub(a, c);
  const float2 t2 = cadd(b, d), t3 = csub(b, d);
  o0 = cadd(t0, t2);
  o2 = csub(t0, t2);
  o1 = cadd(t1, mul_mj(t3));
  o3 = cadd(t1, mul_pj(t3));
}

// in-place 16-pt DFT: v[k] = sum_j v_in[j] * w16^{jk}
__device__ __forceinline__ void dft16(float2 v[16]) {
  float2 A0[4], A1[4], A2[4], A3[4];
  dft4(v[0], v[4], v[ 8], v[12], A0[0], A0[1], A0[2], A0[3]);
  dft4(v[1], v[5], v[ 9], v[13], A1[0], A1[1], A1[2], A1[3]);
  dft4(v[2], v[6], v[10], v[14], A2[0], A2[1], A2[2], A2[3]);
  dft4(v[3], v[7], v[11], v[15], A3[0], A3[1], A3[2], A3[3]);
  dft4(A0[0],       A1[0],        A2[0],        A3[0],       v[0], v[4], v[ 8], v[12]);
  dft4(A0[1], tw1f(A1[1]), tw2f(A2[1]), tw3f(A3[1]), v[1], v[5], v[ 9], v[13]);
  dft4(A0[2], tw2f(A1[2]), mul_mj(A2[2]), tw6f(A3[2]), v[2], v[6], v[10], v[14]);
  dft4(A0[3], tw3f(A1[3]), tw6f(A2[3]), tw9f(A3[3]), v[3], v[7], v[11], v[15]);
}

// serial twiddle chain: v[s] *= w1^s for s = 1..15 (round-6 proven codegen)
__device__ __forceinline__ void twiddle_chain(float2 v[16], const float2 w1) {
  float2 w = w1;
  #pragma unroll
  for (int s = 1; s < 16; ++s) { v[s] = cmul(v[s], w); w = cmul(w, w1); }
}

// 1024-pt FFT for ONE wave: input v[j] = x[l + 64 j]; output natural-order Z in
// zw[PADZ(k)]. Decomposition 1024 = 16 x 16 x 4, two LDS exchanges.
// Twiddles: register cmul chains from 2 global loads (round-9 lesson: the
// 30-load table variant cost +26 us at 12 waves/CU).
// Exchange layouts are phase-specific swizzles, audited conflict-free per
// 16-lane quarter on both store and read sides.
__device__ __forceinline__ void wave_fft1024(float2* __restrict__ zw, float2 v[16],
                                             const int l,
                                             const float2* __restrict__ gtw) {
  // stage A: z_s[l] = w1024^{l s} * sum_j x[l+64j] w16^{js}
  dft16(v);
  twiddle_chain(v, gtw[l]);
  // exchange 1: E[s][l] at 64s + ((l + 4s) & 63)
  // store: stride-1 rotated (conflict-free); read bank = (n0 + 4(r+sp)) mod 16
  // -> bijective over each (sp,n0) quarter (conflict-free).
  #pragma unroll
  for (int s = 0; s < 16; ++s) zw[(s << 6) + ((l + 4 * s) & 63)] = v[s];
  FENCE();
  const int sp = l >> 2, n0 = l & 3;
  #pragma unroll
  for (int r = 0; r < 16; ++r)
    v[r] = zw[(sp << 6) + ((n0 + 4 * r + 4 * sp) & 63)];
  // stage B: g_u = w64^{n0 u} * sum_r z_sp[n0+4r] w16^{ru}
  dft16(v);
  twiddle_chain(v, gtw[n0 << 4]);
  // exchange 2: E2[sp][u][n0] at 64sp + 16(u&3) + 4*(((u>>2)+sp)&3) + ((n0+sp)&3)
  // store bank = 4((a+sp)&3)+((n0+sp)&3); read bank = 4((c+sp)&3)+((m0+sp)&3):
  // both bijective over each 16-lane quarter (conflict-free).
  #pragma unroll
  for (int u = 0; u < 16; ++u)
    zw[(sp << 6) + ((u & 3) << 4) + ((((u >> 2) + sp) & 3) << 2) + ((n0 + sp) & 3)] = v[u];
  FENCE();
  #pragma unroll
  for (int b = 0; b < 4; ++b)
    #pragma unroll
    for (int m0 = 0; m0 < 4; ++m0)
      v[4 * b + m0] = zw[(sp << 6) + (b << 4) + (((n0 + sp) & 3) << 2) + ((m0 + sp) & 3)];
  FENCE();   // all reads retired before stores overwrite the buffer
  // final radix-4: Z[256 q2 + 64 n0 + 16 b + sp] at PADZ (conflict-free:
  // store bank = (sp + 4n0 + b) mod 16; untangle read bank = l mod 16)
  #pragma unroll
  for (int b = 0; b < 4; ++b) {
    float2 o0, o1, o2, o3;
    dft4(v[4*b+0], v[4*b+1], v[4*b+2], v[4*b+3], o0, o1, o2, o3);
    const int kb = 64 * n0 + 16 * b + sp;
    zw[PADZ(kb      )] = o0;
    zw[PADZ(kb + 256)] = o1;
    zw[PADZ(kb + 512)] = o2;
    zw[PADZ(kb + 768)] = o3;
  }
  FENCE();
}

// untangle rfft2048 from packed Z, writing results IN PLACE into zw[slot].x:
// MODE 0: M[i]=|X[i]| ; MODE 1: P[i]=|X[i]|^2 ; MODE 2: R[k]=Re X[k] (k 1..511),
// R[512]=0.  Slot map: value index i lives at zw[PADZ(i)].x (i=1024 -> slot 1088).
// WAR-safe: iteration c reads slots {k=l+64c} (monotone up) and {1024-k>=513}
// (monotone down); writes of iter c hit slots <= 64c+63 and >= 1024-64c-63,
// both strictly outside all later reads. Same-lane same-slot is DS-in-order.
template<int MODE>
__device__ __forceinline__ void untangle(float2* __restrict__ zw,
                                         const int l,
                                         const float2* __restrict__ guw) {
  #pragma unroll
  for (int c = 0; c < 8; ++c) {
    const int k = l + 64 * c;                 // 0..511
    const int m = (1024 - k) & 1023;
    const float2 Zk = zw[PADZ(k)];
    const float2 Zm = zw[PADZ(m)];
    const float Er = 0.5f * (Zk.x + Zm.x), Ei = 0.5f * (Zk.y - Zm.y);
    const float Or = 0.5f * (Zk.y + Zm.y), Oi = 0.5f * (Zm.x - Zk.x);
    const float2 w = guw[k];
    const float wOr = w.x * Or - w.y * Oi;
    const float wOi = w.x * Oi + w.y * Or;
    if (MODE == 2) {
      if (k >= 1) zw[PADZ(k)].x = Er + wOr;
    } else {
      const float Xr = Er + wOr, Xi =  Ei + wOi;
      const float Yr = Er - wOr, Yi = -Ei + wOi;
      if (MODE == 0) {
        zw[PADZ(k)].x        = sqrtf(Xr * Xr + Xi * Xi);
        zw[PADZ(1024 - k)].x = sqrtf(Yr * Yr + Yi * Yi);
      } else {
        zw[PADZ(k)].x        = Xr * Xr + Xi * Xi;
        zw[PADZ(1024 - k)].x = Yr * Yr + Yi * Yi;
      }
    }
  }
  if (l == 0) {            // bin 512: |X[512]| = |Z[512]| ; R[512] masked to 0
    const float2 Z5 = zw[PADZ(512)];
    if (MODE == 0)      zw[PADZ(512)].x = sqrtf(Z5.x * Z5.x + Z5.y * Z5.y);
    else if (MODE == 1) zw[PADZ(512)].x = Z5.x * Z5.x + Z5.y * Z5.y;
    else                zw[PADZ(512)].x = 0.0f;
  }
}

// Fused: one WAVE per frame; plain f0 stores; median is a separate kernel
// (round-8 lesson: per-block agent-scope ACQ_REL atomics poison L2).
// launch_bounds (256,3): proven no-spill allocation (round 6: 72 VGPR;
// (256,4) forced a 64-VGPR target and spilled v[16] -> 3.6x regression).
__global__ __launch_bounds__(256, 3) void pitch_main(const float* __restrict__ audio,
    int N, int T, float* __restrict__ f0,
    const float* __restrict__ gwin, const float2* __restrict__ gtw,
    const float2* __restrict__ guw) {
  __shared__ float2 zbuf[4][1092];     // per-wave workspace (max slot 1088), 34.9 KB
  const int wv = threadIdx.x >> 6;
  const int l  = threadIdx.x & 63;
  const int frame = blockIdx.x * 4 + wv;
  if (frame >= T) return;
  float2* zw = zbuf[wv];
  float2  v[16];

  // ---- pass 1: window + pack x[i] = a[2i] w[2i] + j a[2i+1] w[2i+1] ----
  const int base = frame * HOP - 1024;
  if (base >= 0 && base + 2048 <= N) {
    const float2* au2 = (const float2*)(audio + base);
    const float2* wi2 = (const float2*)gwin;
    #pragma unroll
    for (int j = 0; j < 16; ++j) {
      const float2 a = au2[l + 64 * j];
      const float2 w = wi2[l + 64 * j];
      v[j] = make_float2(a.x * w.x, a.y * w.y);
    }
  } else {                                   // 8 edge frames: reflect pad
    #pragma unroll
    for (int j = 0; j < 16; ++j) {
      const int i2 = 2 * (l + 64 * j);
      int j0 = base + i2, j1 = base + i2 + 1;
      j0 = (j0 < 0) ? -j0 : j0; j0 = (j0 >= N) ? (2 * N - 2 - j0) : j0;
      j1 = (j1 < 0) ? -j1 : j1; j1 = (j1 >= N) ? (2 * N - 2 - j1) : j1;
      v[j] = make_float2(audio[j0] * gwin[i2], audio[j1] * gwin[i2 + 1]);
    }
  }
  wave_fft1024(zw, v, l, gtw);
  untangle<0>(zw, l, guw);                   // M[i] in zw[PADZ(i)].x
  FENCE();

  // ---- pass 2: pack z2[i] = M[2i] + j M[2i+1] (M == 0 past 1024) ----
  #pragma unroll
  for (int j = 0; j < 8; ++j) {
    const int i = l + 64 * j;                // 0..511
    v[j] = make_float2(zw[PADZ(2 * i)].x, zw[PADZ(2 * i + 1)].x);
  }
  {
    const float mv = zw[1088].x;             // M[1024], broadcast read
    v[8] = make_float2((l == 0) ? mv : 0.0f, 0.0f);
    #pragma unroll
    for (int j = 9; j < 16; ++j) v[j] = make_float2(0.0f, 0.0f);
  }
  wave_fft1024(zw, v, l, gtw);
  untangle<1>(zw, l, guw);                   // P[i] in zw[PADZ(i)].x
  FENCE();

  // ---- pass 3: pack z3[i] = Pe[2i] + j Pe[2i+1], Pe = even extension ----
  #pragma unroll
  for (int j = 0; j < 8; ++j) {
    const int i = l + 64 * j;                // direct half, i <= 511
    v[j] = make_float2(zw[PADZ(2 * i)].x, zw[PADZ(2 * i + 1)].x);
  }
  #pragma unroll
  for (int j = 8; j < 16; ++j) {             // mirrored half, i >= 512
    const int i  = l + 64 * j;
    const int e0 = 2048 - 2 * i;             // 2..1024 (i=512 -> P[1024])
    v[j] = make_float2(zw[PADZ(e0)].x, zw[PADZ(e0 - 1)].x);
  }
  wave_fft1024(zw, v, l, gtw);
  untangle<2>(zw, l, guw);                   // R[k] in zw[PADZ(k)].x
  FENCE();

  // ---- peak detect: any k in [2,511] with R[k] > R[k-1] && R[k] > R[k+1]
  int cond = 0;
  #pragma unroll
  for (int c = 0; c < 8; ++c) {
    const int k = l + 64 * c;
    if (k >= 2) {
      const float c0 = zw[PADZ(k)].x;
      if (c0 > zw[PADZ(k - 1)].x && c0 > zw[PADZ(k + 1)].x) cond = 1;
    }
  }
  const int has = __any(cond);
  if (l == 0) f0[frame] = has ? 50.0f : 0.0f;
}

// Median-of-5 smoothing with edge clamp (jnp.pad mode='edge').
__global__ __launch_bounds__(256) void median5_kernel(const float* __restrict__ f0,
                                                      float* __restrict__ out, int T) {
  const int t = blockIdx.x * blockDim.x + threadIdx.x;
  if (t >= T) return;
  float v[5];
  #pragma unroll
  for (int m = 0; m < 5; ++m) {
    int idx = t + m - 2;
    idx = idx < 0 ? 0 : (idx > T - 1 ? T - 1 : idx);
    v[m] = f0[idx];
  }
  #define SW(a,b) { float lo = fminf(v[a], v[b]); float hi = fmaxf(v[a], v[b]); v[a] = lo; v[b] = hi; }
  SW(0,1); SW(3,4); SW(2,4); SW(2,3); SW(1,4); SW(0,3); SW(0,2); SW(1,3); SW(1,2);
  #undef SW
  out[t] = v[2];
}

extern "C" void kernel_launch(void* const* d_in, const int* in_sizes, int n_in,
                              void* d_out, int out_size, void* d_ws, size_t ws_size,
                              hipStream_t stream) {
  const float* audio = (const float*)d_in[0];
  const int n = in_sizes[0];          // 2097152
  const int T = n / HOP + 1;          // 8193

  float* ws    = (float*)d_ws;
  float* f0    = ws;                  // [0, 8193)
  float* win   = ws + 8200;           // 2048 floats, 16B-aligned
  float2* gtw  = (float2*)(ws + 10248); // 512 float2
  float2* guw  = (float2*)(ws + 11272); // 513 float2

  precompute<<<8, 256, 0, stream>>>(win, gtw, guw);
  pitch_main<<<(T + 3) / 4, 256, 0, stream>>>(audio, n, T, f0, win, gtw, guw);
  median5_kernel<<<(T + 255) / 256, 256, 0, stream>>>(f0, (float*)d_out, T);
}

// Round 11
// 113.300 us; speedup vs baseline: 2.6310x; 1.0419x over previous
//
#include <hip/hip_runtime.h>
#include <math.h>

#define HOP 256
#define PI2F 6.28318530717958647692f
// XOR bank swizzle on a power-of-2 float2 buffer: bijective, spreads the
// stride-64/mirror/final-store patterns across all 16 bank-pairs.
#define SWZ(i) ((i) ^ (((i) >> 4) & 15))

#define C16 0.92387953251128675613f   // cos(pi/8)
#define S16 0.38268343236508977173f   // sin(pi/8)
#define RH  0.70710678118654752440f   // sqrt(2)/2

// wave-internal LDS ordering fence: drain LDS queue, pin scheduler.
#define FENCE() do { asm volatile("s_waitcnt lgkmcnt(0)" ::: "memory"); \
                     __builtin_amdgcn_sched_barrier(0); } while (0)

// ---------------- one-time tables (recomputed every launch into d_ws) --------
// win[2048]: periodic Hann; gtw[512]: e^{-j2pi m/1024}; guw[513]: e^{-j2pi k/2048}
__global__ __launch_bounds__(256) void precompute(float* __restrict__ win,
                                                  float2* __restrict__ gtw,
                                                  float2* __restrict__ guw) {
  const int i = blockIdx.x * blockDim.x + threadIdx.x;
  if (i < 2048) win[i] = 0.5f * (1.0f - cosf(PI2F * (float)i / 2048.0f));
  if (i < 512) {
    float s, c; sincosf(-PI2F * (float)i / 1024.0f, &s, &c);
    gtw[i] = make_float2(c, s);
  }
  if (i < 513) {
    float s, c; sincosf(-PI2F * (float)i / 2048.0f, &s, &c);
    guw[i] = make_float2(c, s);
  }
}

// ---------------- complex helpers (forward convention w16 = e^{-j2pi/16}) ----
__device__ __forceinline__ float2 cadd(float2 a, float2 b){ return make_float2(a.x+b.x, a.y+b.y); }
__device__ __forceinline__ float2 csub(float2 a, float2 b){ return make_float2(a.x-b.x, a.y-b.y); }
__device__ __forceinline__ float2 cmul(float2 a, float2 b){
  return make_float2(fmaf(a.x, b.x, -a.y*b.y), fmaf(a.x, b.y, a.y*b.x));
}
__device__ __forceinline__ float2 mul_mj(float2 v){ return make_float2(v.y, -v.x); }  // *(-j)
__device__ __forceinline__ float2 mul_pj(float2 v){ return make_float2(-v.y, v.x); }  // *(+j)
// multiply by w16^e
__device__ __forceinline__ float2 tw1f(float2 v){ return make_float2(fmaf(C16,v.x, S16*v.y), fmaf(C16,v.y,-S16*v.x)); }
__device__ __forceinline__ float2 tw2f(float2 v){ return make_float2(RH*(v.x+v.y), RH*(v.y-v.x)); }
__device__ __forceinline__ float2 tw3f(float2 v){ return make_float2(fmaf(S16,v.x, C16*v.y), fmaf(S16,v.y,-C16*v.x)); }
__device__ __forceinline__ float2 tw6f(float2 v){ return make_float2(RH*(v.y-v.x), -RH*(v.x+v.y)); }
__device__ __forceinline__ float2 tw9f(float2 v){ return make_float2(fmaf(-C16,v.x,-S16*v.y), fmaf(S16,v.x,-C16*v.y)); }

__device__ __forceinline__ void dft4(float2 a, float2 b, float2 c, float2 d,
                                     float2& o0, float2& o1, float2& o2, float2& o3) {
  const float2 t0 = cadd(a, c), t1 = csub(a, c);
  const float2 t2 = cadd(b, d), t3 = csub(b, d);
  o0 = cadd(t0, t2);
  o2 = csub(t0, t2);
  o1 = cadd(t1, mul_mj(t3));
  o3 = cadd(t1, mul_pj(t3));
}

// in-place 16-pt DFT: v[k] = sum_j v_in[j] * w16^{jk}
__device__ __forceinline__ void dft16(float2 v[16]) {
  float2 A0[4], A1[4], A2[4], A3[4];
  dft4(v[0], v[4], v[ 8], v[12], A0[0], A0[1], A0[2], A0[3]);
  dft4(v[1], v[5], v[ 9], v[13], A1[0], A1[1], A1[2], A1[3]);
  dft4(v[2], v[6], v[10], v[14], A2[0], A2[1], A2[2], A2[3]);
  dft4(v[3], v[7], v[11], v[15], A3[0], A3[1], A3[2], A3[3]);
  dft4(A0[0],       A1[0],        A2[0],        A3[0],       v[0], v[4], v[ 8], v[12]);
  dft4(A0[1], tw1f(A1[1]), tw2f(A2[1]), tw3f(A3[1]), v[1], v[5], v[ 9], v[13]);
  dft4(A0[2], tw2f(A1[2]), mul_mj(A2[2]), tw6f(A3[2]), v[2], v[6], v[10], v[14]);
  dft4(A0[3], tw3f(A1[3]), tw6f(A2[3]), tw9f(A3[3]), v[3], v[7], v[11], v[15]);
}

// serial twiddle chain: v[s] *= w1^s for s = 1..15 (round-6 proven codegen;
// only 2 live w registers -> protects the 84-VGPR no-spill allocation)
__device__ __forceinline__ void twiddle_chain(float2 v[16], const float2 w1) {
  float2 w = w1;
  #pragma unroll
  for (int s = 1; s < 16; ++s) { v[s] = cmul(v[s], w); w = cmul(w, w1); }
}

// 1024-pt FFT for ONE wave: input v[j] = x[l + 64 j]; output natural-order Z in
// zw[SWZ(k)]. Decomposition 1024 = 16 x 16 x 4, two LDS exchanges.
// Exchange layouts (raw addressing, audited round 10): conflict-free per
// 16-lane quarter on both store and read sides. Final store uses SWZ
// (store bank-pair = sp ^ (4n0+b): 4 solutions per target = b64 floor).
__device__ __forceinline__ void wave_fft1024(float2* __restrict__ zw, float2 v[16],
                                             const int l,
                                             const float2* __restrict__ gtw) {
  // stage A: z_s[l] = w1024^{l s} * sum_j x[l+64j] w16^{js}
  dft16(v);
  twiddle_chain(v, gtw[l]);
  // exchange 1: E[s][l] at 64s + ((l + 4s) & 63)
  #pragma unroll
  for (int s = 0; s < 16; ++s) zw[(s << 6) + ((l + 4 * s) & 63)] = v[s];
  FENCE();
  const int sp = l >> 2, n0 = l & 3;
  #pragma unroll
  for (int r = 0; r < 16; ++r)
    v[r] = zw[(sp << 6) + ((n0 + 4 * r + 4 * sp) & 63)];
  // stage B: g_u = w64^{n0 u} * sum_r z_sp[n0+4r] w16^{ru}
  dft16(v);
  twiddle_chain(v, gtw[n0 << 4]);
  // exchange 2: E2[sp][u][n0] at 64sp + 16(u&3) + 4*(((u>>2)+sp)&3) + ((n0+sp)&3)
  #pragma unroll
  for (int u = 0; u < 16; ++u)
    zw[(sp << 6) + ((u & 3) << 4) + ((((u >> 2) + sp) & 3) << 2) + ((n0 + sp) & 3)] = v[u];
  FENCE();
  #pragma unroll
  for (int b = 0; b < 4; ++b)
    #pragma unroll
    for (int m0 = 0; m0 < 4; ++m0)
      v[4 * b + m0] = zw[(sp << 6) + (b << 4) + (((n0 + sp) & 3) << 2) + ((m0 + sp) & 3)];
  FENCE();   // all reads retired before stores overwrite the buffer
  // final radix-4: Z[256 q2 + 64 n0 + 16 b + sp] at SWZ slots
  #pragma unroll
  for (int b = 0; b < 4; ++b) {
    float2 o0, o1, o2, o3;
    dft4(v[4*b+0], v[4*b+1], v[4*b+2], v[4*b+3], o0, o1, o2, o3);
    const int kb = 64 * n0 + 16 * b + sp;
    zw[SWZ(kb      )] = o0;
    zw[SWZ(kb + 256)] = o1;
    zw[SWZ(kb + 512)] = o2;
    zw[SWZ(kb + 768)] = o3;
  }
  FENCE();
}

// untangle rfft2048 from packed Z, writing results IN PLACE into zw[SWZ(i)].x.
// MODE 0: M[i]=|X[i]| ; MODE 1: P[i]=|X[i]|^2 ; MODE 2: R[k]=Re X[k] (k 1..511),
// R[512]=0.  Value index 1024 (the k==0 Y-branch) is produced by lane 0 and
// consumed by lane 0 only -> carried in the hi1024 REGISTER, so the buffer
// holds exactly 1024 slots (power-of-2, enables SWZ + 32 KB/block).
// WAR-safe: SWZ is a bijection value->slot; writes at iter c touch exactly the
// value indices read at iter c; later iters read disjoint value indices.
template<int MODE>
__device__ __forceinline__ void untangle(float2* __restrict__ zw,
                                         const int l,
                                         const float2* __restrict__ guw,
                                         float& hi1024) {
  #pragma unroll
  for (int c = 0; c < 8; ++c) {
    const int k = l + 64 * c;                 // 0..511
    const int m = (1024 - k) & 1023;
    const float2 Zk = zw[SWZ(k)];
    const float2 Zm = zw[SWZ(m)];
    const float Er = 0.5f * (Zk.x + Zm.x), Ei = 0.5f * (Zk.y - Zm.y);
    const float Or = 0.5f * (Zk.y + Zm.y), Oi = 0.5f * (Zm.x - Zk.x);
    const float2 w = guw[k];
    const float wOr = w.x * Or - w.y * Oi;
    const float wOi = w.x * Oi + w.y * Or;
    if (MODE == 2) {
      if (k >= 1) zw[SWZ(k)].x = Er + wOr;
    } else {
      const float Xr = Er + wOr, Xi =  Ei + wOi;
      const float Yr = Er - wOr, Yi = -Ei + wOi;
      const float Xv = (MODE == 0) ? sqrtf(Xr * Xr + Xi * Xi) : (Xr * Xr + Xi * Xi);
      const float Yv = (MODE == 0) ? sqrtf(Yr * Yr + Yi * Yi) : (Yr * Yr + Yi * Yi);
      zw[SWZ(k)].x = Xv;
      if (k == 0) hi1024 = Yv;                // value index 1024, lane 0 only
      else        zw[SWZ(1024 - k)].x = Yv;
    }
  }
  if (l == 0) {            // bin 512: |X[512]| = |Z[512]| ; R[512] masked to 0
    const float2 Z5 = zw[SWZ(512)];
    if (MODE == 0)      zw[SWZ(512)].x = sqrtf(Z5.x * Z5.x + Z5.y * Z5.y);
    else if (MODE == 1) zw[SWZ(512)].x = Z5.x * Z5.x + Z5.y * Z5.y;
    else                zw[SWZ(512)].x = 0.0f;
  }
}

// Fused: one WAVE per frame; plain f0 stores; median is a separate kernel
// (round-8 lesson: per-block agent-scope ACQ_REL atomics poison L2).
// launch_bounds (256,3): proven no-spill allocation (round 6: 72 VGPR;
// (256,4) forced a 64-VGPR target and spilled v[16] -> 3.6x regression).
// zbuf = 4 x 1024 float2 = 32 KB exactly -> 5 blocks/CU (160 KB).
__global__ __launch_bounds__(256, 3) void pitch_main(const float* __restrict__ audio,
    int N, int T, float* __restrict__ f0,
    const float* __restrict__ gwin, const float2* __restrict__ gtw,
    const float2* __restrict__ guw) {
  __shared__ float2 zbuf[4][1024];
  const int wv = threadIdx.x >> 6;
  const int l  = threadIdx.x & 63;
  const int frame = blockIdx.x * 4 + wv;
  if (frame >= T) return;
  float2* zw = zbuf[wv];
  float2  v[16];
  float   hi1024 = 0.0f;               // M[1024] then P[1024] (lane 0)

  // ---- pass 1: window + pack x[i] = a[2i] w[2i] + j a[2i+1] w[2i+1] ----
  const int base = frame * HOP - 1024;
  if (base >= 0 && base + 2048 <= N) {
    const float2* au2 = (const float2*)(audio + base);
    const float2* wi2 = (const float2*)gwin;
    #pragma unroll
    for (int j = 0; j < 16; ++j) {
      const float2 a = au2[l + 64 * j];
      const float2 w = wi2[l + 64 * j];
      v[j] = make_float2(a.x * w.x, a.y * w.y);
    }
  } else {                                   // 8 edge frames: reflect pad
    #pragma unroll
    for (int j = 0; j < 16; ++j) {
      const int i2 = 2 * (l + 64 * j);
      int j0 = base + i2, j1 = base + i2 + 1;
      j0 = (j0 < 0) ? -j0 : j0; j0 = (j0 >= N) ? (2 * N - 2 - j0) : j0;
      j1 = (j1 < 0) ? -j1 : j1; j1 = (j1 >= N) ? (2 * N - 2 - j1) : j1;
      v[j] = make_float2(audio[j0] * gwin[i2], audio[j1] * gwin[i2 + 1]);
    }
  }
  wave_fft1024(zw, v, l, gtw);
  untangle<0>(zw, l, guw, hi1024);           // M[i] in zw[SWZ(i)].x, M[1024] in reg
  FENCE();

  // ---- pass 2: pack z2[i] = M[2i] + j M[2i+1] (M == 0 past 1024) ----
  #pragma unroll
  for (int j = 0; j < 8; ++j) {
    const int i = l + 64 * j;                // 0..511
    v[j] = make_float2(zw[SWZ(2 * i)].x, zw[SWZ(2 * i + 1)].x);
  }
  v[8] = make_float2((l == 0) ? hi1024 : 0.0f, 0.0f);   // i = 512: (M[1024], 0)
  #pragma unroll
  for (int j = 9; j < 16; ++j) v[j] = make_float2(0.0f, 0.0f);
  wave_fft1024(zw, v, l, gtw);
  untangle<1>(zw, l, guw, hi1024);           // P[i] in zw[SWZ(i)].x, P[1024] in reg
  FENCE();

  // ---- pass 3: pack z3[i] = Pe[2i] + j Pe[2i+1], Pe = even extension ----
  #pragma unroll
  for (int j = 0; j < 8; ++j) {
    const int i = l + 64 * j;                // direct half, i <= 511
    v[j] = make_float2(zw[SWZ(2 * i)].x, zw[SWZ(2 * i + 1)].x);
  }
  #pragma unroll
  for (int j = 8; j < 16; ++j) {             // mirrored half, i >= 512
    const int i  = l + 64 * j;
    if (j == 8 && l == 0) {
      v[j] = make_float2(hi1024, zw[SWZ(1023)].x);      // (P[1024], P[1023])
    } else {
      const int e0 = 2048 - 2 * i;           // 2..1022
      v[j] = make_float2(zw[SWZ(e0)].x, zw[SWZ(e0 - 1)].x);
    }
  }
  wave_fft1024(zw, v, l, gtw);
  untangle<2>(zw, l, guw, hi1024);           // R[k] in zw[SWZ(k)].x
  FENCE();

  // ---- peak detect: any k in [2,511] with R[k] > R[k-1] && R[k] > R[k+1]
  int cond = 0;
  #pragma unroll
  for (int c = 0; c < 8; ++c) {
    const int k = l + 64 * c;
    if (k >= 2) {
      const float c0 = zw[SWZ(k)].x;
      if (c0 > zw[SWZ(k - 1)].x && c0 > zw[SWZ(k + 1)].x) cond = 1;
    }
  }
  const int has = __any(cond);
  if (l == 0) f0[frame] = has ? 50.0f : 0.0f;
}

// Median-of-5 smoothing with edge clamp (jnp.pad mode='edge').
__global__ __launch_bounds__(256) void median5_kernel(const float* __restrict__ f0,
                                                      float* __restrict__ out, int T) {
  const int t = blockIdx.x * blockDim.x + threadIdx.x;
  if (t >= T) return;
  float v[5];
  #pragma unroll
  for (int m = 0; m < 5; ++m) {
    int idx = t + m - 2;
    idx = idx < 0 ? 0 : (idx > T - 1 ? T - 1 : idx);
    v[m] = f0[idx];
  }
  #define SW(a,b) { float lo = fminf(v[a], v[b]); float hi = fmaxf(v[a], v[b]); v[a] = lo; v[b] = hi; }
  SW(0,1); SW(3,4); SW(2,4); SW(2,3); SW(1,4); SW(0,3); SW(0,2); SW(1,3); SW(1,2);
  #undef SW
  out[t] = v[2];
}

extern "C" void kernel_launch(void* const* d_in, const int* in_sizes, int n_in,
                              void* d_out, int out_size, void* d_ws, size_t ws_size,
                              hipStream_t stream) {
  const float* audio = (const float*)d_in[0];
  const int n = in_sizes[0];          // 2097152
  const int T = n / HOP + 1;          // 8193

  float* ws    = (float*)d_ws;
  float* f0    = ws;                  // [0, 8193)
  float* win   = ws + 8200;           // 2048 floats, 16B-aligned
  float2* gtw  = (float2*)(ws + 10248); // 512 float2
  float2* guw  = (float2*)(ws + 11272); // 513 float2

  precompute<<<8, 256, 0, stream>>>(win, gtw, guw);
  pitch_main<<<(T + 3) / 4, 256, 0, stream>>>(audio, n, T, f0, win, gtw, guw);
  median5_kernel<<<(T + 255) / 256, 256, 0, stream>>>(f0, (float*)d_out, T);
}